// Round 2
// baseline (506.240 us; speedup 1.0000x reference)
//
#include <hip/hip_runtime.h>
#include <math.h>

#define NB 8
#define NS 4
#define NP 4096
#define HID 4096
#define NHQ 32
#define NHKV 8
#define ND 128
#define NGROUP 4
#define NBS 32      /* NB*NS rows */
#define NQI 16      /* NGROUP*NS q-rows per (b,kv) */
#define QKV_COLS 6144
#define LOG2E 1.4426950408889634f

// ---------------- transpose x (32 x 4096) -> xT (4096 x 32) ----------------
__global__ __launch_bounds__(256) void prep_xT(const float* __restrict__ x,
                                               float* __restrict__ xT) {
  int n = blockIdx.x * 256 + threadIdx.x;  // n < 131072
  int r = n >> 12;
  int k = n & 4095;
  xT[k * NBS + r] = x[n];
}

// ---------------- RoPE: q -> q_t[(b,kv)][d][i], k_new -> [(b,kv)][s][d] ----
__global__ __launch_bounds__(256) void rope_kernel(
    const float* __restrict__ qb, const float* __restrict__ kb,
    const float* __restrict__ cosp, const float* __restrict__ sinp,
    const int* __restrict__ past_len, float* __restrict__ q_t,
    float* __restrict__ k_new) {
  int n = blockIdx.x * 256 + threadIdx.x;
  int pl = past_len[0];
  if (n < NBS * HID) {  // q element
    int r = n >> 12;    // b*4+s
    int hd = n & 4095;
    int h = hd >> 7, d = hd & 127;
    int b = r >> 2, s = r & 3;
    int pos = pl + s;
    float c = cosp[pos * ND + d], sn = sinp[pos * ND + d];
    float v = qb[n];
    float other = (d < 64) ? -qb[n + 64] : qb[n - 64];
    float rv = fmaf(v, c, other * sn);
    int kv = h >> 2, g = h & 3;
    q_t[(((b * NHKV + kv) * ND + d) * NQI) + g * NS + s] = rv;
  } else {  // k element
    n -= NBS * HID;  // n < 32768
    int r = n >> 10;
    int hd = n & 1023;
    int kv = hd >> 7, d = hd & 127;
    int b = r >> 2, s = r & 3;
    int pos = pl + s;
    float c = cosp[pos * ND + d], sn = sinp[pos * ND + d];
    float v = kb[n];
    float other = (d < 64) ? -kb[n + 64] : kb[n - 64];
    k_new[((b * NHKV + kv) * NS + s) * ND + d] = fmaf(v, c, other * sn);
  }
}

// -------- GEMM partials: P[kb][32][ncols] = A_T-slice x W-slice ------------
template <int KSLICE>
__global__ __launch_bounds__(256) void gemm_part(
    const float* __restrict__ A_T, const float* __restrict__ wq,
    const float* __restrict__ wk, const float* __restrict__ wv,
    const float* __restrict__ wo, float* __restrict__ P, int mode) {
  __shared__ __align__(16) float lds[8192];  // x-stage, then tree-reduce (32KB)
  int cb = blockIdx.x, kb = blockIdx.y;
  int ncols = mode ? 4096 : QKV_COLS;
  int col0 = cb * 128;
  const float* W;
  int ld, wcol;
  if (mode) {
    W = wo; ld = 4096; wcol = col0;
  } else if (col0 < 4096) {
    W = wq; ld = 4096; wcol = col0;
  } else if (col0 < 5120) {
    W = wk; ld = 1024; wcol = col0 - 4096;
  } else {
    W = wv; ld = 1024; wcol = col0 - 5120;
  }
  int tid = threadIdx.x;
  int lane = tid & 63;
  int wid = __builtin_amdgcn_readfirstlane(tid >> 6);
  int l32 = lane & 31;
  int mh = lane >> 5;  // m-half
  int kblk = kb * KSLICE;
  constexpr int KW = KSLICE / 4;
  int k0 = wid * KW;
  const float* wp = W + (size_t)(kblk + k0) * ld + wcol + l32 * 4;

  float4 wb[8];
#pragma unroll
  for (int u = 0; u < 8; u++) wb[u] = *(const float4*)(wp + (size_t)u * ld);

  {
    const float4* src = (const float4*)(A_T + (size_t)kblk * NBS);
    float4* dst = (float4*)lds;
#pragma unroll
    for (int p = 0; p < KSLICE / 32; p++)
      dst[p * 256 + tid] = src[p * 256 + tid];
  }
  __syncthreads();

  float acc[64];
#pragma unroll
  for (int v = 0; v < 64; v++) acc[v] = 0.f;

  const float* xp = lds + (size_t)k0 * NBS + mh * 16;

  auto body = [&](int kk, float4 w) {
    const float* xr = xp + (size_t)kk * NBS;
    float4 xa = *(const float4*)(xr);
    float4 xb = *(const float4*)(xr + 4);
    float4 xc = *(const float4*)(xr + 8);
    float4 xd = *(const float4*)(xr + 12);
    float xm[16] = {xa.x, xa.y, xa.z, xa.w, xb.x, xb.y, xb.z, xb.w,
                    xc.x, xc.y, xc.z, xc.w, xd.x, xd.y, xd.z, xd.w};
#pragma unroll
    for (int m = 0; m < 16; m++) {
      acc[4 * m + 0] = fmaf(xm[m], w.x, acc[4 * m + 0]);
      acc[4 * m + 1] = fmaf(xm[m], w.y, acc[4 * m + 1]);
      acc[4 * m + 2] = fmaf(xm[m], w.z, acc[4 * m + 2]);
      acc[4 * m + 3] = fmaf(xm[m], w.w, acc[4 * m + 3]);
    }
  };

#pragma unroll 8
  for (int kk = 0; kk < KW - 8; kk++) {
    float4 w = wb[kk & 7];
    wb[kk & 7] = *(const float4*)(wp + (size_t)(kk + 8) * ld);  // prefetch
    body(kk, w);
  }
#pragma unroll
  for (int kk = KW - 8; kk < KW; kk++) {
    float4 w = wb[kk & 7];
    body(kk, w);
  }

  __syncthreads();
  if (wid >= 2) {
#pragma unroll
    for (int v = 0; v < 64; v++) lds[(wid - 2) * 4096 + v * 64 + lane] = acc[v];
  }
  __syncthreads();
  if (wid < 2) {
#pragma unroll
    for (int v = 0; v < 64; v++) acc[v] += lds[wid * 4096 + v * 64 + lane];
  }
  __syncthreads();
  if (wid == 1) {
#pragma unroll
    for (int v = 0; v < 64; v++) lds[v * 64 + lane] = acc[v];
  }
  __syncthreads();
  if (wid == 0) {
#pragma unroll
    for (int v = 0; v < 64; v++) acc[v] += lds[v * 64 + lane];
#pragma unroll
    for (int m = 0; m < 16; m++) {
      float4 st = make_float4(acc[4 * m], acc[4 * m + 1], acc[4 * m + 2],
                              acc[4 * m + 3]);
      *(float4*)(P + ((size_t)kb * NBS + mh * 16 + m) * ncols + col0 +
                 l32 * 4) = st;
    }
  }
}

// ---------------- reduce partials: qkv -> qb/kb/vb -------------------------
template <int KS>
__global__ __launch_bounds__(256) void reduce_qkv(const float* __restrict__ P,
                                                  float* __restrict__ qb,
                                                  float* __restrict__ kbuf,
                                                  float* __restrict__ vbuf) {
  size_t idx = ((size_t)blockIdx.x * 256 + threadIdx.x) * 4;  // < 196608
  float4 s = make_float4(0.f, 0.f, 0.f, 0.f);
#pragma unroll
  for (int p = 0; p < KS; p++) {
    float4 v = *(const float4*)(P + (size_t)p * (NBS * QKV_COLS) + idx);
    s.x += v.x; s.y += v.y; s.z += v.z; s.w += v.w;
  }
  int r = (int)(idx / QKV_COLS);
  int col = (int)(idx % QKV_COLS);
  float* dst;
  if (col < 4096)
    dst = qb + (size_t)r * 4096 + col;
  else if (col < 5120)
    dst = kbuf + (size_t)r * 1024 + (col - 4096);
  else
    dst = vbuf + (size_t)r * 1024 + (col - 5120);
  *(float4*)dst = s;
}

// ---------------- reduce partials: out-proj -> out -------------------------
template <int KS>
__global__ __launch_bounds__(256) void reduce_o(const float* __restrict__ P,
                                                float* __restrict__ outp) {
  size_t idx = ((size_t)blockIdx.x * 256 + threadIdx.x) * 4;  // < 131072
  float4 s = make_float4(0.f, 0.f, 0.f, 0.f);
#pragma unroll
  for (int p = 0; p < KS; p++) {
    float4 v = *(const float4*)(P + (size_t)p * (NBS * 4096) + idx);
    s.x += v.x; s.y += v.y; s.z += v.z; s.w += v.w;
  }
  *(float4*)(outp + idx) = s;
}

// ---------------- attention: grid = (bk, nch), 256 threads -----------------
// TCH=128: 33 chunks, 2 threads/t in score (d-halves, LDS pair-reduce).
// TCH=256: 17 chunks, 1 thread/t.
// PV: 8 groups of 32 lanes = (q-half x t-quarter); o[8][4] = 32 VGPR.
// LDS pool sbuf aliases: score pair-reduce scratch -> p[t][17] -> PV fold.
template <int TCH>
__global__ __launch_bounds__(256, 6) void attn_kernel(
    const float* __restrict__ q_t, const float* __restrict__ k_cache,
    const float* __restrict__ v_cache, const float* __restrict__ k_new,
    const float* __restrict__ vbuf, float* __restrict__ part_o,
    float* __restrict__ part_m, float* __restrict__ part_l, int nch) {
  constexpr int BUFN = (TCH * 17 > 4096) ? TCH * 17 : 4096;
  constexpr int NWS = (TCH == 128) ? 2 : 4;  // waves holding full scores
  constexpr int NF4 = (TCH == 128) ? 16 : 32;
  constexpr int TPV = TCH / 4;  // tokens per PV group
  __shared__ __align__(16) float sbuf[BUFN];
  __shared__ float redm[NQI][4];
  __shared__ float redl[NQI][4];
  __shared__ float mfin[NQI];
  int bk = blockIdx.x;
  int chunk = blockIdx.y;
  int blk = bk * nch + chunk;
  int b = bk >> 3, kv = bk & 7;
  int tid = threadIdx.x;
  int lane = tid & 63;
  int wid = tid >> 6;
  bool last = (chunk == nch - 1);
  int tcount = last ? NS : TCH;
  const float* qbase = q_t + (size_t)bk * (ND * NQI);

  // ---- scores ----
  int t_loc = tid & (TCH - 1);
  int dh = tid / TCH;  // 0 or 1 (TCH=128); always 0 (TCH=256)
  bool tvalid = t_loc < tcount;
  int t_eff = tvalid ? t_loc : 0;
  const float* kp =
      last ? (k_new + ((size_t)bk * NS + t_eff) * ND)
           : (k_cache +
              (((size_t)b * NP + chunk * TCH + t_eff) * NHKV + kv) * ND);
  kp += dh * 64;
  float s_acc[NQI];
#pragma unroll
  for (int i = 0; i < NQI; i++) s_acc[i] = 0.f;
#pragma unroll 4
  for (int i = 0; i < NF4; ++i) {
    float4 kvv = *(const float4*)(kp + i * 4);
    const float* qp = qbase + (dh * 64 + i * 4) * NQI;  // uniform -> s_load
#pragma unroll
    for (int q = 0; q < NQI; q++) {
      float s = s_acc[q];
      s = fmaf(kvv.x, qp[q], s);
      s = fmaf(kvv.y, qp[NQI + q], s);
      s = fmaf(kvv.z, qp[2 * NQI + q], s);
      s = fmaf(kvv.w, qp[3 * NQI + q], s);
      s_acc[q] = s;
    }
  }
  if (TCH == 128) {  // pair-reduce d-halves via LDS
    if (dh == 1) {
#pragma unroll
      for (int q = 0; q < NQI; q++) sbuf[t_loc * 17 + q] = s_acc[q];
    }
    __syncthreads();
    if (dh == 0) {
#pragma unroll
      for (int q = 0; q < NQI; q++) s_acc[q] += sbuf[t_loc * 17 + q];
    }
  }
  const float scale = 0.08838834764831845f;  // 1/sqrt(128)
  float sc[NQI];
#pragma unroll
  for (int q = 0; q < NQI; q++) {
    float s = s_acc[q] * scale;
    if (dh != 0 || !tvalid || (last && t_loc > (q & 3)))
      s = -__builtin_inff();
    sc[q] = s;
  }
  // wave max per q -> LDS (only waves holding scores matter)
#pragma unroll
  for (int q = 0; q < NQI; q++) {
    float m = sc[q];
#pragma unroll
    for (int off = 1; off < 64; off <<= 1) m = fmaxf(m, __shfl_xor(m, off, 64));
    if (lane == 0 && wid < NWS) redm[q][wid] = m;
  }
  __syncthreads();
  if (tid < NQI) {
    float m = redm[tid][0];
#pragma unroll
    for (int w = 1; w < NWS; w++) m = fmaxf(m, redm[tid][w]);
    mfin[tid] = m;
  }
  __syncthreads();
  float l_loc[NQI];
  if (dh == 0) {
#pragma unroll
    for (int q = 0; q < NQI; q++) {
      float p = exp2f((sc[q] - mfin[q]) * LOG2E);
      sbuf[t_loc * 17 + q] = p;
      l_loc[q] = p;
    }
  } else {
#pragma unroll
    for (int q = 0; q < NQI; q++) l_loc[q] = 0.f;
  }
  if (wid < NWS) {
#pragma unroll
    for (int q = 0; q < NQI; q++) {
      float l = l_loc[q];
#pragma unroll
      for (int off = 1; off < 64; off <<= 1) l += __shfl_xor(l, off, 64);
      if (lane == 0) redl[q][wid] = l;
    }
  }
  __syncthreads();  // publishes p in sbuf + redl
  if (tid < NQI) {
    float l = redl[tid][0];
#pragma unroll
    for (int w = 1; w < NWS; w++) l += redl[tid][w];
    part_m[(size_t)blk * NQI + tid] = mfin[tid];
    part_l[(size_t)blk * NQI + tid] = l;
  }

  // ---- PV: group g = (qh, tq); thread: 8 q x 4 d over TPV tokens ----
  int g = tid >> 5;
  int qh = g & 1;   // q-half
  int tq = g >> 1;  // t-quarter; wave w == tq w (both halves same t-range)
  int dq = (tid & 31) * 4;
  int tbeg = tq * TPV;
  int tnum = tcount - tbeg;
  tnum = tnum < 0 ? 0 : (tnum > TPV ? TPV : tnum);
  const float* vpb =
      last ? (vbuf + ((size_t)b * NS + tbeg) * (NHKV * ND) + kv * ND + dq)
           : (v_cache + ((size_t)b * NP + chunk * TCH + tbeg) * (NHKV * ND) +
              kv * ND + dq);
  float o[8][4];
#pragma unroll
  for (int i = 0; i < 8; i++) o[i][0] = o[i][1] = o[i][2] = o[i][3] = 0.f;
#pragma unroll 4
  for (int tt = 0; tt < tnum; ++tt) {
    float4 vv = *(const float4*)(vpb + (size_t)tt * (NHKV * ND));
    const float* pp = sbuf + (tbeg + tt) * 17 + qh * 8;  // group-uniform
#pragma unroll
    for (int i = 0; i < 8; i++) {
      float p = pp[i];
      o[i][0] = fmaf(p, vv.x, o[i][0]);
      o[i][1] = fmaf(p, vv.y, o[i][1]);
      o[i][2] = fmaf(p, vv.z, o[i][2]);
      o[i][3] = fmaf(p, vv.w, o[i][3]);
    }
  }
  __syncthreads();  // p dead -> sbuf becomes fold buffer (needs 4096 floats)
  if (wid >= 2) {   // waves 2,3 (tq 2,3) publish
#pragma unroll
    for (int i = 0; i < 8; i++)
      *(float4*)(sbuf + (wid - 2) * 2048 + i * 256 + lane * 4) =
          make_float4(o[i][0], o[i][1], o[i][2], o[i][3]);
  }
  __syncthreads();
  if (wid < 2) {
#pragma unroll
    for (int i = 0; i < 8; i++) {
      float4 r = *(const float4*)(sbuf + wid * 2048 + i * 256 + lane * 4);
      o[i][0] += r.x; o[i][1] += r.y; o[i][2] += r.z; o[i][3] += r.w;
    }
  }
  __syncthreads();
  if (wid == 1) {
#pragma unroll
    for (int i = 0; i < 8; i++)
      *(float4*)(sbuf + i * 256 + lane * 4) =
          make_float4(o[i][0], o[i][1], o[i][2], o[i][3]);
  }
  __syncthreads();
  if (wid == 0) {
    size_t obase = (size_t)blk * (NQI * ND);
#pragma unroll
    for (int i = 0; i < 8; i++) {
      float4 r = *(const float4*)(sbuf + i * 256 + lane * 4);
      *(float4*)(part_o + obase + (size_t)(qh * 8 + i) * ND + dq) =
          make_float4(o[i][0] + r.x, o[i][1] + r.y, o[i][2] + r.z,
                      o[i][3] + r.w);
    }
  }
}

// ---------------- combine partials -> attn_T (4096 x 32) -------------------
__global__ __launch_bounds__(256) void combine_kernel(
    const float* __restrict__ part_o, const float* __restrict__ part_m,
    const float* __restrict__ part_l, float* __restrict__ attn_T, int nch) {
  int bk = blockIdx.x;
  int tid = threadIdx.x;
  int i = tid >> 4;
  int dh = (tid & 15) * 4 + blockIdx.y * 64;
  float M = -__builtin_inff();
  for (int c = 0; c < nch; c++)
    M = fmaxf(M, part_m[((size_t)bk * nch + c) * NQI + i]);
  float L = 0.f;
  float o0 = 0.f, o1 = 0.f, o2 = 0.f, o3 = 0.f;
  for (int c = 0; c < nch; c++) {
    size_t pc = (size_t)bk * nch + c;
    float mc = part_m[pc * NQI + i];
    float w = exp2f((mc - M) * LOG2E);
    L = fmaf(part_l[pc * NQI + i], w, L);
    float4 po = *(const float4*)(part_o + pc * (NQI * ND) + (size_t)i * ND + dh);
    o0 = fmaf(w, po.x, o0);
    o1 = fmaf(w, po.y, o1);
    o2 = fmaf(w, po.z, o2);
    o3 = fmaf(w, po.w, o3);
  }
  float inv = 1.0f / L;
  int b = bk >> 3, kv = bk & 7;
  int g = i >> 2, s = i & 3;
  int h = kv * NGROUP + g;
  int r = b * NS + s;
  attn_T[(size_t)(h * ND + dh + 0) * NBS + r] = o0 * inv;
  attn_T[(size_t)(h * ND + dh + 1) * NBS + r] = o1 * inv;
  attn_T[(size_t)(h * ND + dh + 2) * NBS + r] = o2 * inv;
  attn_T[(size_t)(h * ND + dh + 3) * NBS + r] = o3 * inv;
}

// ---------------------------------------------------------------------------
extern "C" void kernel_launch(void* const* d_in, const int* in_sizes, int n_in,
                              void* d_out, int out_size, void* d_ws,
                              size_t ws_size, hipStream_t stream) {
  const float* x = (const float*)d_in[0];
  const float* wq = (const float*)d_in[1];
  const float* wk = (const float*)d_in[2];
  const float* wv = (const float*)d_in[3];
  const float* wo = (const float*)d_in[4];
  const float* cosp = (const float*)d_in[5];
  const float* sinp = (const float*)d_in[6];
  const float* k_cache = (const float*)d_in[7];
  const float* v_cache = (const float*)d_in[8];
  const int* past_len = (const int*)d_in[9];
  float* out = (float*)d_out;

  float* ws = (float*)d_ws;
  float* xT = ws;                   // 131072
  float* qb = xT + 131072;          // 131072
  float* kbuf = qb + 131072;        // 32768
  float* vbuf = kbuf + 32768;       // 32768
  float* q_t = vbuf + 32768;        // 131072
  float* k_new = q_t + 131072;      // 32768
  float* attn_T = k_new + 32768;    // 131072
  float* R = attn_T + 131072;       // shared region (Pq / part_o / Po)

  size_t ws_fl = ws_size / sizeof(float);
  // path A: KSPLIT=32, 33 chunks  -> 622592 + 6291456
  // path B: KSPLIT=16, 33 chunks  -> 622592 + 4392960
  // path C: KSPLIT=16, 17 chunks  -> 622592 + 3768320 floats (round-0 size)
  int ksplit, nch;
  if (ws_fl >= (size_t)622592 + 6291456) {
    ksplit = 32; nch = 33;
  } else if (ws_fl >= (size_t)622592 + 4392960) {
    ksplit = 16; nch = 33;
  } else {
    ksplit = 16; nch = 17;
  }
  float* Pq = R;
  float* part_o = R;                            // 64*nch*2048
  float* part_m = R + (size_t)64 * nch * 2048;  // 64*nch*16
  float* part_l = part_m + (size_t)64 * nch * 16;
  float* Po = R;

  prep_xT<<<512, 256, 0, stream>>>(x, xT);
  if (ksplit == 32) {
    gemm_part<128><<<dim3(48, 32), 256, 0, stream>>>(xT, wq, wk, wv, wo, Pq, 0);
    reduce_qkv<32><<<192, 256, 0, stream>>>(Pq, qb, kbuf, vbuf);
  } else {
    gemm_part<256><<<dim3(48, 16), 256, 0, stream>>>(xT, wq, wk, wv, wo, Pq, 0);
    reduce_qkv<16><<<192, 256, 0, stream>>>(Pq, qb, kbuf, vbuf);
  }
  rope_kernel<<<640, 256, 0, stream>>>(qb, kbuf, cosp, sinp, past_len, q_t,
                                       k_new);
  if (nch == 33) {
    attn_kernel<128><<<dim3(64, 33), 256, 0, stream>>>(
        q_t, k_cache, v_cache, k_new, vbuf, part_o, part_m, part_l, 33);
  } else {
    attn_kernel<256><<<dim3(64, 17), 256, 0, stream>>>(
        q_t, k_cache, v_cache, k_new, vbuf, part_o, part_m, part_l, 17);
  }
  combine_kernel<<<dim3(64, 2), 256, 0, stream>>>(part_o, part_m, part_l,
                                                  attn_T, nch);
  if (ksplit == 32) {
    gemm_part<128><<<dim3(32, 32), 256, 0, stream>>>(attn_T, wq, wk, wv, wo,
                                                     Po, 1);
    reduce_o<32><<<128, 256, 0, stream>>>(Po, out);
  } else {
    gemm_part<256><<<dim3(32, 16), 256, 0, stream>>>(attn_T, wq, wk, wv, wo,
                                                     Po, 1);
    reduce_o<16><<<128, 256, 0, stream>>>(Po, out);
  }
}

// Round 3
// 451.971 us; speedup vs baseline: 1.1201x; 1.1201x over previous
//
#include <hip/hip_runtime.h>
#include <math.h>

#define NB 8
#define NS 4
#define NP 4096
#define HID 4096
#define NHQ 32
#define NHKV 8
#define ND 128
#define NGROUP 4
#define NBS 32      /* NB*NS rows */
#define NQI 16      /* NGROUP*NS q-rows per (b,kv) */
#define NCHUNK 17   /* 16 cache chunks of 256 + 1 new-token chunk */
#define TCHUNK 256
#define QKV_COLS 6144
#define LOG2E 1.4426950408889634f

// ---------------- transpose x (32 x 4096) -> xT (4096 x 32) ----------------
__global__ __launch_bounds__(256) void prep_xT(const float* __restrict__ x,
                                               float* __restrict__ xT) {
  int n = blockIdx.x * 256 + threadIdx.x;  // n < 131072
  int r = n >> 12;
  int k = n & 4095;
  xT[k * NBS + r] = x[n];
}

// ---------------- RoPE: q -> q_t[(b,kv)][d][i], k_new -> [(b,kv)][s][d] ----
__global__ __launch_bounds__(256) void rope_kernel(
    const float* __restrict__ qb, const float* __restrict__ kb,
    const float* __restrict__ cosp, const float* __restrict__ sinp,
    const int* __restrict__ past_len, float* __restrict__ q_t,
    float* __restrict__ k_new) {
  int n = blockIdx.x * 256 + threadIdx.x;
  int pl = past_len[0];
  if (n < NBS * HID) {  // q element
    int r = n >> 12;    // b*4+s
    int hd = n & 4095;
    int h = hd >> 7, d = hd & 127;
    int b = r >> 2, s = r & 3;
    int pos = pl + s;
    float c = cosp[pos * ND + d], sn = sinp[pos * ND + d];
    float v = qb[n];
    float other = (d < 64) ? -qb[n + 64] : qb[n - 64];
    float rv = fmaf(v, c, other * sn);
    int kv = h >> 2, g = h & 3;
    q_t[(((b * NHKV + kv) * ND + d) * NQI) + g * NS + s] = rv;
  } else {  // k element
    n -= NBS * HID;  // n < 32768
    int r = n >> 10;
    int hd = n & 1023;
    int kv = hd >> 7, d = hd & 127;
    int b = r >> 2, s = r & 3;
    int pos = pl + s;
    float c = cosp[pos * ND + d], sn = sinp[pos * ND + d];
    float v = kb[n];
    float other = (d < 64) ? -kb[n + 64] : kb[n - 64];
    k_new[((b * NHKV + kv) * NS + s) * ND + d] = fmaf(v, c, other * sn);
  }
}

// -------- async global -> LDS helper (16 B per lane, wave-uniform LDS base) -
__device__ __forceinline__ void gl_lds16(const float* g, float* l) {
  __builtin_amdgcn_global_load_lds(
      (const __attribute__((address_space(1))) void*)g,
      (__attribute__((address_space(3))) void*)l, 16, 0, 0);
}

// -------- GEMM partials: P[kb][32][ncols] = A_T-slice x W-slice ------------
// Tile: 256 cols x KSLICE k-rows per block. W staged via global_load_lds in
// 16-row chunks (16 KB), double-buffered, counted vmcnt(4) (never drained to
// 0 in the loop) so 4-8 load-instructions stay in flight per wave. Each wave
// owns 8 m-rows -> direct coalesced stores, no reduce tree. Every W HBM
// request is 1 KB contiguous (16 cache lines).
template <int KSLICE>
__global__ __launch_bounds__(256) void gemm_part(
    const float* __restrict__ A_T, const float* __restrict__ wq,
    const float* __restrict__ wk, const float* __restrict__ wv,
    const float* __restrict__ wo, float* __restrict__ P, int mode) {
  constexpr int NCH = KSLICE / 16;      // 16-k chunks per block
  __shared__ __align__(16) float xs[KSLICE * 32];   // x-slice [k][m]
  __shared__ __align__(16) float wbuf[2 * 16 * 256];  // W dbuf [k][col]
  int cb = blockIdx.x, kb = blockIdx.y;
  int ncols = mode ? 4096 : QKV_COLS;
  int col0 = cb * 256;
  const float* W;
  int ld, wcol;
  if (mode) {
    W = wo; ld = 4096; wcol = col0;
  } else if (col0 < 4096) {
    W = wq; ld = 4096; wcol = col0;
  } else if (col0 < 5120) {
    W = wk; ld = 1024; wcol = col0 - 4096;
  } else {
    W = wv; ld = 1024; wcol = col0 - 5120;
  }
  int tid = threadIdx.x;
  int lane = tid & 63;
  int wid = __builtin_amdgcn_readfirstlane(tid >> 6);
  int lane4 = lane * 4;
  int m0 = wid * 8;
  int kblk = kb * KSLICE;
  const float* wbase = W + (size_t)kblk * ld + wcol;

  // prologue: issue x-stage, then W chunks 0 and 1
#pragma unroll
  for (int j = 0; j < KSLICE / 32; j++) {
    // wave-uniform LDS base; global contiguous 1 KB per wave
    gl_lds16(A_T + (size_t)kblk * 32 + j * 1024 + wid * 256 + lane4,
             xs + j * 1024 + wid * 256);
  }
#pragma unroll
  for (int j = 0; j < 4; j++) {  // chunk 0
    int row = j * 4 + wid;
    gl_lds16(wbase + (size_t)row * ld + lane4, wbuf + row * 256);
  }
#pragma unroll
  for (int j = 0; j < 4; j++) {  // chunk 1
    int row = j * 4 + wid;
    gl_lds16(wbase + (size_t)(16 + row) * ld + lane4,
             wbuf + 4096 + row * 256);
  }

  float acc[8][4];
#pragma unroll
  for (int m = 0; m < 8; m++)
    acc[m][0] = acc[m][1] = acc[m][2] = acc[m][3] = 0.f;

#pragma unroll 1
  for (int c = 0; c < NCH; c++) {
    if (c < NCH - 1)
      asm volatile("s_waitcnt vmcnt(4)" ::: "memory");
    else
      asm volatile("s_waitcnt vmcnt(0)" ::: "memory");
    __builtin_amdgcn_s_barrier();
    asm volatile("" ::: "memory");

    const float* wbp = wbuf + (c & 1) * 4096;
    const float* xcp = xs + c * 512 + m0;
#pragma unroll
    for (int k = 0; k < 16; k++) {
      float4 w4 = *(const float4*)(wbp + k * 256 + lane4);
      const float* xr = xcp + k * 32;
      float4 xa = *(const float4*)(xr);
      float4 xb = *(const float4*)(xr + 4);
      float xm[8] = {xa.x, xa.y, xa.z, xa.w, xb.x, xb.y, xb.z, xb.w};
#pragma unroll
      for (int m = 0; m < 8; m++) {
        acc[m][0] = fmaf(xm[m], w4.x, acc[m][0]);
        acc[m][1] = fmaf(xm[m], w4.y, acc[m][1]);
        acc[m][2] = fmaf(xm[m], w4.z, acc[m][2]);
        acc[m][3] = fmaf(xm[m], w4.w, acc[m][3]);
      }
    }

    asm volatile("" ::: "memory");
    __builtin_amdgcn_s_barrier();
    if (c + 2 < NCH) {  // overwrite the buffer compute(c) just released
#pragma unroll
      for (int j = 0; j < 4; j++) {
        int row = j * 4 + wid;
        gl_lds16(wbase + (size_t)((c + 2) * 16 + row) * ld + lane4,
                 wbuf + (c & 1) * 4096 + row * 256);
      }
    }
  }

  // store: wave wid owns m0..m0+7, lanes cover 256 cols (1 KB contiguous)
#pragma unroll
  for (int m = 0; m < 8; m++) {
    *(float4*)(P + ((size_t)kb * NBS + m0 + m) * ncols + col0 + lane4) =
        make_float4(acc[m][0], acc[m][1], acc[m][2], acc[m][3]);
  }
}

// ---------------- reduce partials: qkv -> qb/kb/vb -------------------------
template <int KS>
__global__ __launch_bounds__(256) void reduce_qkv(const float* __restrict__ P,
                                                  float* __restrict__ qb,
                                                  float* __restrict__ kbuf,
                                                  float* __restrict__ vbuf) {
  size_t idx = ((size_t)blockIdx.x * 256 + threadIdx.x) * 4;  // < 196608
  float4 s = make_float4(0.f, 0.f, 0.f, 0.f);
#pragma unroll
  for (int p = 0; p < KS; p++) {
    float4 v = *(const float4*)(P + (size_t)p * (NBS * QKV_COLS) + idx);
    s.x += v.x; s.y += v.y; s.z += v.z; s.w += v.w;
  }
  int r = (int)(idx / QKV_COLS);
  int col = (int)(idx % QKV_COLS);
  float* dst;
  if (col < 4096)
    dst = qb + (size_t)r * 4096 + col;
  else if (col < 5120)
    dst = kbuf + (size_t)r * 1024 + (col - 4096);
  else
    dst = vbuf + (size_t)r * 1024 + (col - 5120);
  *(float4*)dst = s;
}

// ---------------- reduce partials: out-proj -> out -------------------------
template <int KS>
__global__ __launch_bounds__(256) void reduce_o(const float* __restrict__ P,
                                                float* __restrict__ outp) {
  size_t idx = ((size_t)blockIdx.x * 256 + threadIdx.x) * 4;  // < 131072
  float4 s = make_float4(0.f, 0.f, 0.f, 0.f);
#pragma unroll
  for (int p = 0; p < KS; p++) {
    float4 v = *(const float4*)(P + (size_t)p * (NBS * 4096) + idx);
    s.x += v.x; s.y += v.y; s.z += v.z; s.w += v.w;
  }
  *(float4*)(outp + idx) = s;
}

// ---------------- attention: grid = (bk, chunk), 256 threads ---------------
// (round-0 structure: fastest measured at 112 us)
__global__ __launch_bounds__(256) void attn_kernel(
    const float* __restrict__ q_t, const float* __restrict__ k_cache,
    const float* __restrict__ v_cache, const float* __restrict__ k_new,
    const float* __restrict__ vbuf, float* __restrict__ part_o,
    float* __restrict__ part_m, float* __restrict__ part_l) {
  __shared__ float p_lds[TCHUNK * 17];  // stride 17: conflict-free
  __shared__ float redm[NQI][4];
  __shared__ float redl[NQI][4];
  __shared__ float mfin[NQI];
  int bk = blockIdx.x;
  int chunk = blockIdx.y;
  int blk = bk * NCHUNK + chunk;
  int b = bk >> 3, kv = bk & 7;
  int tid = threadIdx.x;
  int lane = tid & 63;
  int wid = tid >> 6;
  bool last = (chunk == NCHUNK - 1);
  int tcount = last ? NS : TCHUNK;
  const float* qbase = q_t + (size_t)bk * (ND * NQI);

  // ---- scores: one thread per t, full d ----
  int t_loc = tid;
  bool valid = t_loc < tcount;
  int t_eff = valid ? t_loc : 0;
  const float* kp =
      last ? (k_new + ((size_t)bk * NS + t_eff) * ND)
           : (k_cache +
              (((size_t)b * NP + chunk * TCHUNK + t_eff) * NHKV + kv) * ND);
  float s_acc[NQI];
#pragma unroll
  for (int i = 0; i < NQI; i++) s_acc[i] = 0.f;
#pragma unroll 8
  for (int d4 = 0; d4 < 32; ++d4) {
    float4 kvv = *(const float4*)(kp + d4 * 4);
    const float* qp = qbase + (d4 * 4) * NQI;  // uniform -> s_load
#pragma unroll
    for (int i = 0; i < NQI; i++) {
      float s = s_acc[i];
      s = fmaf(kvv.x, qp[i], s);
      s = fmaf(kvv.y, qp[NQI + i], s);
      s = fmaf(kvv.z, qp[2 * NQI + i], s);
      s = fmaf(kvv.w, qp[3 * NQI + i], s);
      s_acc[i] = s;
    }
  }
  const float scale = 0.08838834764831845f;  // 1/sqrt(128)
  float sc[NQI];
#pragma unroll
  for (int i = 0; i < NQI; i++) {
    float s = s_acc[i] * scale;
    if (!valid || (last && t_loc > (i & 3))) s = -__builtin_inff();
    sc[i] = s;
  }
  // wave max per i -> LDS
#pragma unroll
  for (int i = 0; i < NQI; i++) {
    float m = sc[i];
#pragma unroll
    for (int off = 1; off < 64; off <<= 1) m = fmaxf(m, __shfl_xor(m, off, 64));
    if (lane == 0) redm[i][wid] = m;
  }
  __syncthreads();
  if (tid < NQI) {
    float m = fmaxf(fmaxf(redm[tid][0], redm[tid][1]),
                    fmaxf(redm[tid][2], redm[tid][3]));
    mfin[tid] = m;
  }
  __syncthreads();
  float l_loc[NQI];
#pragma unroll
  for (int i = 0; i < NQI; i++) {
    float p = exp2f((sc[i] - mfin[i]) * LOG2E);
    p_lds[t_loc * 17 + i] = p;
    l_loc[i] = p;
  }
#pragma unroll
  for (int i = 0; i < NQI; i++) {
    float l = l_loc[i];
#pragma unroll
    for (int off = 1; off < 64; off <<= 1) l += __shfl_xor(l, off, 64);
    if (lane == 0) redl[i][wid] = l;
  }
  __syncthreads();
  if (tid < NQI) {
    float l = redl[tid][0] + redl[tid][1] + redl[tid][2] + redl[tid][3];
    part_m[(size_t)blk * NQI + tid] = mfin[tid];
    part_l[(size_t)blk * NQI + tid] = l;
  }

  // ---- PV: thread -> 2 q-rows (r0, r0+8) x 4 d ----
  int r0 = tid >> 5;
  int dq = (tid & 31) * 4;
  const float* vpb =
      last ? (vbuf + (size_t)b * NS * (NHKV * ND) + kv * ND + dq)
           : (v_cache + ((size_t)b * NP + chunk * TCHUNK) * (NHKV * ND) +
              kv * ND + dq);
  float o0[4] = {0, 0, 0, 0}, o1[4] = {0, 0, 0, 0};
#pragma unroll 8
  for (int t = 0; t < tcount; ++t) {
    float4 vv = *(const float4*)(vpb + (size_t)t * (NHKV * ND));
    float p0 = p_lds[t * 17 + r0];
    float p1 = p_lds[t * 17 + r0 + 8];
    o0[0] = fmaf(p0, vv.x, o0[0]); o0[1] = fmaf(p0, vv.y, o0[1]);
    o0[2] = fmaf(p0, vv.z, o0[2]); o0[3] = fmaf(p0, vv.w, o0[3]);
    o1[0] = fmaf(p1, vv.x, o1[0]); o1[1] = fmaf(p1, vv.y, o1[1]);
    o1[2] = fmaf(p1, vv.z, o1[2]); o1[3] = fmaf(p1, vv.w, o1[3]);
  }
  size_t obase = (size_t)blk * (NQI * ND);
  *(float4*)(part_o + obase + (size_t)r0 * ND + dq) =
      make_float4(o0[0], o0[1], o0[2], o0[3]);
  *(float4*)(part_o + obase + (size_t)(r0 + 8) * ND + dq) =
      make_float4(o1[0], o1[1], o1[2], o1[3]);
}

// ---------------- combine partials -> attn_T (4096 x 32) -------------------
__global__ __launch_bounds__(256) void combine_kernel(
    const float* __restrict__ part_o, const float* __restrict__ part_m,
    const float* __restrict__ part_l, float* __restrict__ attn_T) {
  int bk = blockIdx.x;
  int tid = threadIdx.x;
  int i = tid >> 4;
  int dh = (tid & 15) * 4 + blockIdx.y * 64;
  float M = -__builtin_inff();
#pragma unroll
  for (int c = 0; c < NCHUNK; c++)
    M = fmaxf(M, part_m[((size_t)bk * NCHUNK + c) * NQI + i]);
  float L = 0.f;
  float o0 = 0.f, o1 = 0.f, o2 = 0.f, o3 = 0.f;
#pragma unroll
  for (int c = 0; c < NCHUNK; c++) {
    size_t pc = (size_t)bk * NCHUNK + c;
    float mc = part_m[pc * NQI + i];
    float w = exp2f((mc - M) * LOG2E);
    L = fmaf(part_l[pc * NQI + i], w, L);
    float4 po = *(const float4*)(part_o + pc * (NQI * ND) + (size_t)i * ND + dh);
    o0 = fmaf(w, po.x, o0);
    o1 = fmaf(w, po.y, o1);
    o2 = fmaf(w, po.z, o2);
    o3 = fmaf(w, po.w, o3);
  }
  float inv = 1.0f / L;
  int b = bk >> 3, kv = bk & 7;
  int g = i >> 2, s = i & 3;
  int h = kv * NGROUP + g;
  int r = b * NS + s;
  attn_T[(size_t)(h * ND + dh + 0) * NBS + r] = o0 * inv;
  attn_T[(size_t)(h * ND + dh + 1) * NBS + r] = o1 * inv;
  attn_T[(size_t)(h * ND + dh + 2) * NBS + r] = o2 * inv;
  attn_T[(size_t)(h * ND + dh + 3) * NBS + r] = o3 * inv;
}

// ---------------------------------------------------------------------------
extern "C" void kernel_launch(void* const* d_in, const int* in_sizes, int n_in,
                              void* d_out, int out_size, void* d_ws,
                              size_t ws_size, hipStream_t stream) {
  const float* x = (const float*)d_in[0];
  const float* wq = (const float*)d_in[1];
  const float* wk = (const float*)d_in[2];
  const float* wv = (const float*)d_in[3];
  const float* wo = (const float*)d_in[4];
  const float* cosp = (const float*)d_in[5];
  const float* sinp = (const float*)d_in[6];
  const float* k_cache = (const float*)d_in[7];
  const float* v_cache = (const float*)d_in[8];
  const int* past_len = (const int*)d_in[9];
  float* out = (float*)d_out;

  float* ws = (float*)d_ws;
  float* xT = ws;                   // 131072
  float* qb = xT + 131072;          // 131072
  float* kbuf = qb + 131072;        // 32768
  float* vbuf = kbuf + 32768;       // 32768
  float* q_t = vbuf + 32768;        // 131072
  float* k_new = q_t + 131072;      // 32768
  float* attn_T = k_new + 32768;    // 131072
  float* R = attn_T + 131072;       // shared region (Pq / part_o / Po)
  float* Pq = R;                    // KSPLIT*32*6144 (dead after reduce)
  float* part_o = R;                // 64*17*2048 = 2228224 (dead after combine)
  float* part_m = R + 2228224;      // 17408
  float* part_l = part_m + 17408;   // 17408
  float* Po = R;                    // KSPLIT*32*4096

  // KSPLIT=32 path needs 622592 + 32*32*6144 floats (27.7 MB) — same budget
  // round 2's path A used. Fallback: KSPLIT=16 (KSLICE 256).
  const size_t need32 = (size_t)(622592 + 32 * NBS * QKV_COLS) * sizeof(float);
  const bool big = ws_size >= need32;

  prep_xT<<<512, 256, 0, stream>>>(x, xT);
  if (big) {
    gemm_part<128><<<dim3(24, 32), 256, 0, stream>>>(xT, wq, wk, wv, wo, Pq, 0);
    reduce_qkv<32><<<192, 256, 0, stream>>>(Pq, qb, kbuf, vbuf);
  } else {
    gemm_part<256><<<dim3(24, 16), 256, 0, stream>>>(xT, wq, wk, wv, wo, Pq, 0);
    reduce_qkv<16><<<192, 256, 0, stream>>>(Pq, qb, kbuf, vbuf);
  }
  rope_kernel<<<640, 256, 0, stream>>>(qb, kbuf, cosp, sinp, past_len, q_t,
                                       k_new);
  attn_kernel<<<dim3(64, NCHUNK), 256, 0, stream>>>(
      q_t, k_cache, v_cache, k_new, vbuf, part_o, part_m, part_l);
  combine_kernel<<<dim3(64, 2), 256, 0, stream>>>(part_o, part_m, part_l,
                                                  attn_T);
  if (big) {
    gemm_part<128><<<dim3(16, 32), 256, 0, stream>>>(attn_T, wq, wk, wv, wo,
                                                     Po, 1);
    reduce_o<32><<<128, 256, 0, stream>>>(Po, out);
  } else {
    gemm_part<256><<<dim3(16, 16), 256, 0, stream>>>(attn_T, wq, wk, wv, wo,
                                                     Po, 1);
    reduce_o<16><<<128, 256, 0, stream>>>(Po, out);
  }
}